// Round 10
// baseline (154.515 us; speedup 1.0000x reference)
//
#include <hip/hip_runtime.h>

#define NB_CAT  8192
#define RANK    16
#define N_COLS  4
#define N_PAIRS 1048576

#define NSLICE      8                         // (col, rank-half)
#define SLICE_ROWS  NB_CAT                    // rows of 16 B (8 fp16)
#define SLICE_BYTES (SLICE_ROWS * 16)         // 128 KB
#define TBL_BYTES   ((size_t)NSLICE * SLICE_BYTES)  // 1 MB
#define LDS_BYTES   SLICE_BYTES               // single buffer, 128 KB

typedef _Float16 half2_t __attribute__((ext_vector_type(2)));

#if defined(__has_builtin)
#if __has_builtin(__builtin_amdgcn_fdot2)
#define HAVE_FDOT2 1
#endif
#endif

__device__ __forceinline__ float dot8_f16(uint4 A, uint4 B, float acc) {
#ifdef HAVE_FDOT2
    acc = __builtin_amdgcn_fdot2(__builtin_bit_cast(half2_t, A.x), __builtin_bit_cast(half2_t, B.x), acc, false);
    acc = __builtin_amdgcn_fdot2(__builtin_bit_cast(half2_t, A.y), __builtin_bit_cast(half2_t, B.y), acc, false);
    acc = __builtin_amdgcn_fdot2(__builtin_bit_cast(half2_t, A.z), __builtin_bit_cast(half2_t, B.z), acc, false);
    acc = __builtin_amdgcn_fdot2(__builtin_bit_cast(half2_t, A.w), __builtin_bit_cast(half2_t, B.w), acc, false);
#else
    half2_t ax = __builtin_bit_cast(half2_t, A.x), bx = __builtin_bit_cast(half2_t, B.x);
    half2_t ay = __builtin_bit_cast(half2_t, A.y), by = __builtin_bit_cast(half2_t, B.y);
    half2_t az = __builtin_bit_cast(half2_t, A.z), bz = __builtin_bit_cast(half2_t, B.z);
    half2_t aw = __builtin_bit_cast(half2_t, A.w), bw = __builtin_bit_cast(half2_t, B.w);
    acc = fmaf((float)ax[0], (float)bx[0], acc); acc = fmaf((float)ax[1], (float)bx[1], acc);
    acc = fmaf((float)ay[0], (float)by[0], acc); acc = fmaf((float)ay[1], (float)by[1], acc);
    acc = fmaf((float)az[0], (float)bz[0], acc); acc = fmaf((float)az[1], (float)bz[1], acc);
    acc = fmaf((float)aw[0], (float)bw[0], acc); acc = fmaf((float)aw[1], (float)bw[1], acc);
#endif
    return acc;
}

__device__ __forceinline__ int comp4(const int4& v, int c) {
    return (c == 0) ? v.x : (c == 1) ? v.y : (c == 2) ? v.z : v.w;
}

// ---------- prep: fp32 cf -> fp16 table, layout [slice=(c,h)][cat] row = 16 B ----------
__global__ __launch_bounds__(256) void pack_f16_kernel(
    const float4* __restrict__ src,   // cf as float4
    uint4*        __restrict__ dst)   // one uint4 = one 8-half row
{
    const int g = blockIdx.x * 256 + threadIdx.x;   // slice*8192 + cat, 65536 total
    const int s = g >> 13;
    const int k = g & (NB_CAT - 1);
    const int c = s >> 1, h = s & 1;

    const float4 f0 = src[(c * NB_CAT + k) * 4 + h * 2];
    const float4 f1 = src[(c * NB_CAT + k) * 4 + h * 2 + 1];

    half2_t p0 = {(_Float16)f0.x, (_Float16)f0.y};
    half2_t p1 = {(_Float16)f0.z, (_Float16)f0.w};
    half2_t p2 = {(_Float16)f1.x, (_Float16)f1.y};
    half2_t p3 = {(_Float16)f1.z, (_Float16)f1.w};

    uint4 u;
    u.x = __builtin_bit_cast(unsigned int, p0);
    u.y = __builtin_bit_cast(unsigned int, p1);
    u.z = __builtin_bit_cast(unsigned int, p2);
    u.w = __builtin_bit_cast(unsigned int, p3);
    dst[g] = u;
}

// ---------- main: b128 gather rows, single-buffer + register-prefetch pipeline ----------
// 256 blocks x 1024 threads, 128 KB dyn LDS, 4096 pairs/block (4/thread).
// Phase s (slice = (col s>>1, half s&1)): prefetch slice s+1 into regs (global,
// in flight during compute), compute slice s (8 ds_read_b128/thread + fdot2),
// barrier, ds_write slice s+1 from regs, lgkm-barrier. 8 phases, 2 barriers each.
__global__ __launch_bounds__(1024, 1) void IndexKernel_32238024524411_kernel(
    const int4*  __restrict__ x4,    // (N_PAIRS) int4
    const int4*  __restrict__ y4,
    const uint4* __restrict__ tbl,   // fp16 table in ws
    const float* __restrict__ stdv,  // (N_COLS, NB_CAT) fp32
    float*       __restrict__ out)
{
    extern __shared__ uint4 sh[];    // SLICE_ROWS = 8192 rows

    const int tid  = threadIdx.x;
    const int base = blockIdx.x * 4096 + tid;

    // coalesced one-time index loads
    int4 xv[4], yv[4];
#pragma unroll
    for (int j = 0; j < 4; ++j) {
        xv[j] = x4[base + j * 1024];
        yv[j] = y4[base + j * 1024];
    }

    float acc[4] = {0.f, 0.f, 0.f, 0.f};

    // diagonal std^2 pre-pass (rare; keeps the phase loop free of global vmem)
#pragma unroll
    for (int j = 0; j < 4; ++j) {
        const int4 a = xv[j], b = yv[j];
        if (a.x == b.x) { const float s = stdv[0 * NB_CAT + a.x]; acc[j] = fmaf(s, s, acc[j]); }
        if (a.y == b.y) { const float s = stdv[1 * NB_CAT + a.y]; acc[j] = fmaf(s, s, acc[j]); }
        if (a.z == b.z) { const float s = stdv[2 * NB_CAT + a.z]; acc[j] = fmaf(s, s, acc[j]); }
        if (a.w == b.w) { const float s = stdv[3 * NB_CAT + a.w]; acc[j] = fmaf(s, s, acc[j]); }
    }

    // prologue: stage slice 0
    uint4 stg[8];
#pragma unroll
    for (int it = 0; it < 8; ++it) stg[it] = tbl[tid + it * 1024];
#pragma unroll
    for (int it = 0; it < 8; ++it) sh[tid + it * 1024] = stg[it];
    asm volatile("s_waitcnt lgkmcnt(0)" ::: "memory");
    __builtin_amdgcn_s_barrier();
    asm volatile("" ::: "memory");

#pragma unroll
    for (int s = 0; s < NSLICE; ++s) {
        const int c = s >> 1;

        // prefetch slice s+1 into registers; stays in flight during compute
        if (s < NSLICE - 1) {
            const uint4* nsrc = tbl + (size_t)(s + 1) * SLICE_ROWS;
#pragma unroll
            for (int it = 0; it < 8; ++it) stg[it] = nsrc[tid + it * 1024];
        }
        asm volatile("" ::: "memory");   // keep prefetch issue above compute

        // compute slice s: full 16-B row gathers
#pragma unroll
        for (int j = 0; j < 4; ++j) {
            const int xi = comp4(xv[j], c);
            const int yi = comp4(yv[j], c);
            const uint4 a = sh[xi];
            const uint4 b = sh[yi];
            acc[j] = dot8_f16(a, b, acc[j]);
        }

        if (s < NSLICE - 1) {
            // all waves' reads done (each wave's reads are consumed by fdot2
            // before it reaches the barrier)
            asm volatile("s_waitcnt lgkmcnt(0)" ::: "memory");
            __builtin_amdgcn_s_barrier();
            asm volatile("" ::: "memory");
            // overwrite the buffer with slice s+1 (vmcnt wait auto-inserted on stg use)
#pragma unroll
            for (int it = 0; it < 8; ++it) sh[tid + it * 1024] = stg[it];
            asm volatile("s_waitcnt lgkmcnt(0)" ::: "memory");
            __builtin_amdgcn_s_barrier();
            asm volatile("" ::: "memory");
        }
    }

#pragma unroll
    for (int j = 0; j < 4; ++j) {
        out[base + j * 1024] = acc[j];
    }
}

// ---------- fallback (fp32 direct gather, R3 structure) if ws too small ----------
__global__ __launch_bounds__(256) void fallback_kernel(
    const int* __restrict__ x, const int* __restrict__ y,
    const float4* __restrict__ cf, const float* __restrict__ stdv,
    float* __restrict__ out)
{
    const int tid = threadIdx.x;
    const int q = tid & 15, gi = tid >> 4, c = q >> 2, s = q & 3;
    const int p0 = blockIdx.x * 32 + gi, p1 = p0 + 16;
    const int rb = c * NB_CAT;
    const int xi0 = x[p0*4+c], yi0 = y[p0*4+c], xi1 = x[p1*4+c], yi1 = y[p1*4+c];
    const float4 a0 = cf[(size_t)(rb+xi0)*4 + s], b0 = cf[(size_t)(rb+yi0)*4 + s];
    const float4 a1 = cf[(size_t)(rb+xi1)*4 + s], b1 = cf[(size_t)(rb+yi1)*4 + s];
    float v0 = a0.x*b0.x; v0 = fmaf(a0.y,b0.y,v0); v0 = fmaf(a0.z,b0.z,v0); v0 = fmaf(a0.w,b0.w,v0);
    float v1 = a1.x*b1.x; v1 = fmaf(a1.y,b1.y,v1); v1 = fmaf(a1.z,b1.z,v1); v1 = fmaf(a1.w,b1.w,v1);
    if (s == 0 && xi0 == yi0) { float sd = stdv[rb+xi0]; v0 = fmaf(sd,sd,v0); }
    if (s == 0 && xi1 == yi1) { float sd = stdv[rb+yi1]; v1 = fmaf(sd,sd,v1); }
    int t;
    t = __builtin_amdgcn_update_dpp(0, __float_as_int(v0), 0xB1, 0xF, 0xF, true); v0 += __int_as_float(t);
    t = __builtin_amdgcn_update_dpp(0, __float_as_int(v0), 0x4E, 0xF, 0xF, true); v0 += __int_as_float(t);
    t = __builtin_amdgcn_update_dpp(0, __float_as_int(v0), 0x141,0xF, 0xF, true); v0 += __int_as_float(t);
    t = __builtin_amdgcn_update_dpp(0, __float_as_int(v0), 0x128,0xF, 0xF, true); v0 += __int_as_float(t);
    t = __builtin_amdgcn_update_dpp(0, __float_as_int(v1), 0xB1, 0xF, 0xF, true); v1 += __int_as_float(t);
    t = __builtin_amdgcn_update_dpp(0, __float_as_int(v1), 0x4E, 0xF, 0xF, true); v1 += __int_as_float(t);
    t = __builtin_amdgcn_update_dpp(0, __float_as_int(v1), 0x141,0xF, 0xF, true); v1 += __int_as_float(t);
    t = __builtin_amdgcn_update_dpp(0, __float_as_int(v1), 0x128,0xF, 0xF, true); v1 += __int_as_float(t);
    if (q == 0) { out[p0] = v0; out[p1] = v1; }
}

extern "C" void kernel_launch(void* const* d_in, const int* in_sizes, int n_in,
                              void* d_out, int out_size, void* d_ws, size_t ws_size,
                              hipStream_t stream) {
    const int*   x    = (const int*)d_in[0];
    const int*   y    = (const int*)d_in[1];
    const float* cf   = (const float*)d_in[2];
    const float* stdv = (const float*)d_in[3];
    float*       out  = (float*)d_out;

    if (ws_size < TBL_BYTES) {
        fallback_kernel<<<N_PAIRS / 32, 256, 0, stream>>>(
            x, y, (const float4*)cf, stdv, out);
        return;
    }

    (void)hipFuncSetAttribute(
        reinterpret_cast<const void*>(&IndexKernel_32238024524411_kernel),
        hipFuncAttributeMaxDynamicSharedMemorySize, LDS_BYTES);

    pack_f16_kernel<<<NSLICE * NB_CAT / 256, 256, 0, stream>>>(
        (const float4*)cf, (uint4*)d_ws);

    IndexKernel_32238024524411_kernel<<<N_PAIRS / 4096, 1024, LDS_BYTES, stream>>>(
        (const int4*)x, (const int4*)y, (const uint4*)d_ws, stdv, out);
}

// Round 11
// 101.834 us; speedup vs baseline: 1.5173x; 1.5173x over previous
//
#include <hip/hip_runtime.h>

#define NB_CAT  8192
#define RANK    16
#define N_COLS  4
#define N_PAIRS 1048576

#define NSLICE       8                          // (col, rank-half), b128 rows
#define SLICE_ROWS   NB_CAT
#define SLICE_BYTES  (SLICE_ROWS * 16)          // 128 KB
#define TBL_SM_BYTES ((size_t)NSLICE * SLICE_BYTES)    // 1 MB slice-major (LDS staging)
#define TBL_RM_BYTES ((size_t)N_COLS * NB_CAT * 32)    // 1 MB row-major (TCP gathers)
#define WS_NEED      (TBL_SM_BYTES + TBL_RM_BYTES)     // 2 MB
#define LDS_BYTES    SLICE_BYTES

#define NLDS_THR 832      // 13 waves -> LDS path
#define LDS_PPB  3328     // 832 * 4 pairs
#define TCP_PPP  96       // TCP pairs per phase (x8 phases = 768/block)

typedef _Float16 half2_t __attribute__((ext_vector_type(2)));

#if defined(__has_builtin)
#if __has_builtin(__builtin_amdgcn_fdot2)
#define HAVE_FDOT2 1
#endif
#endif

__device__ __forceinline__ float dot8_f16(uint4 A, uint4 B, float acc) {
#ifdef HAVE_FDOT2
    acc = __builtin_amdgcn_fdot2(__builtin_bit_cast(half2_t, A.x), __builtin_bit_cast(half2_t, B.x), acc, false);
    acc = __builtin_amdgcn_fdot2(__builtin_bit_cast(half2_t, A.y), __builtin_bit_cast(half2_t, B.y), acc, false);
    acc = __builtin_amdgcn_fdot2(__builtin_bit_cast(half2_t, A.z), __builtin_bit_cast(half2_t, B.z), acc, false);
    acc = __builtin_amdgcn_fdot2(__builtin_bit_cast(half2_t, A.w), __builtin_bit_cast(half2_t, B.w), acc, false);
#else
    half2_t ax = __builtin_bit_cast(half2_t, A.x), bx = __builtin_bit_cast(half2_t, B.x);
    half2_t ay = __builtin_bit_cast(half2_t, A.y), by = __builtin_bit_cast(half2_t, B.y);
    half2_t az = __builtin_bit_cast(half2_t, A.z), bz = __builtin_bit_cast(half2_t, B.z);
    half2_t aw = __builtin_bit_cast(half2_t, A.w), bw = __builtin_bit_cast(half2_t, B.w);
    acc = fmaf((float)ax[0], (float)bx[0], acc); acc = fmaf((float)ax[1], (float)bx[1], acc);
    acc = fmaf((float)ay[0], (float)by[0], acc); acc = fmaf((float)ay[1], (float)by[1], acc);
    acc = fmaf((float)az[0], (float)bz[0], acc); acc = fmaf((float)az[1], (float)bz[1], acc);
    acc = fmaf((float)aw[0], (float)bw[0], acc); acc = fmaf((float)aw[1], (float)bw[1], acc);
#endif
    return acc;
}

// 8-lane group sum, pure VALU DPP (quad_perm x2 + row_half_mirror)
__device__ __forceinline__ float groupsum8(float v) {
    int t;
    t = __builtin_amdgcn_update_dpp(0, __float_as_int(v), 0xB1, 0xF, 0xF, true);
    v += __int_as_float(t);
    t = __builtin_amdgcn_update_dpp(0, __float_as_int(v), 0x4E, 0xF, 0xF, true);
    v += __int_as_float(t);
    t = __builtin_amdgcn_update_dpp(0, __float_as_int(v), 0x141, 0xF, 0xF, true);
    v += __int_as_float(t);
    return v;
}

__device__ __forceinline__ int comp4(const int4& v, int c) {
    return (c == 0) ? v.x : (c == 1) ? v.y : (c == 2) ? v.z : v.w;
}

// ---------- prep: fp32 cf -> fp16, BOTH layouts ----------
// slice-major: [slice=(c,h)][cat], row = 16 B   (for LDS staging)
// row-major:   [c][cat], row = 32 B = 2 chunks  (for TCP gathers, R4 geometry)
__global__ __launch_bounds__(256) void pack_f16_kernel(
    const float4* __restrict__ src, uint4* __restrict__ sm, uint4* __restrict__ rm)
{
    const int g = blockIdx.x * 256 + threadIdx.x;   // slice*8192 + cat, 65536
    const int s = g >> 13;
    const int k = g & (NB_CAT - 1);
    const int c = s >> 1, h = s & 1;

    const float4 f0 = src[(c * NB_CAT + k) * 4 + h * 2];
    const float4 f1 = src[(c * NB_CAT + k) * 4 + h * 2 + 1];

    half2_t p0 = {(_Float16)f0.x, (_Float16)f0.y};
    half2_t p1 = {(_Float16)f0.z, (_Float16)f0.w};
    half2_t p2 = {(_Float16)f1.x, (_Float16)f1.y};
    half2_t p3 = {(_Float16)f1.z, (_Float16)f1.w};

    uint4 u;
    u.x = __builtin_bit_cast(unsigned int, p0);
    u.y = __builtin_bit_cast(unsigned int, p1);
    u.z = __builtin_bit_cast(unsigned int, p2);
    u.w = __builtin_bit_cast(unsigned int, p3);
    sm[g] = u;
    rm[(size_t)(c * NB_CAT + k) * 2 + h] = u;
}

// ---------- main: hybrid — LDS pipe (13 waves) + TCP pipe (3 waves) per CU ----------
__global__ __launch_bounds__(1024, 1) void IndexKernel_32238024524411_kernel(
    const int4*  __restrict__ x4, const int4* __restrict__ y4,
    const int*   __restrict__ x,  const int*  __restrict__ y,
    const uint4* __restrict__ tsm,   // slice-major table
    const uint4* __restrict__ trm,   // row-major table
    const float* __restrict__ stdv,
    float*       __restrict__ out)
{
    extern __shared__ uint4 sh[];    // one 128 KB slice

    const int tid  = threadIdx.x;
    const int base = blockIdx.x * 4096;

    // ---- LDS-path setup (waves 0..12) ----
    int4 xv[4], yv[4];
    float acc[4] = {0.f, 0.f, 0.f, 0.f};
    if (tid < NLDS_THR) {
#pragma unroll
        for (int k = 0; k < 4; ++k) {
            xv[k] = x4[base + tid + k * NLDS_THR];
            yv[k] = y4[base + tid + k * NLDS_THR];
        }
        // diagonal std^2 pre-pass
#pragma unroll
        for (int j = 0; j < 4; ++j) {
            const int4 a = xv[j], b = yv[j];
            if (a.x == b.x) { const float s = stdv[0 * NB_CAT + a.x]; acc[j] = fmaf(s, s, acc[j]); }
            if (a.y == b.y) { const float s = stdv[1 * NB_CAT + a.y]; acc[j] = fmaf(s, s, acc[j]); }
            if (a.z == b.z) { const float s = stdv[2 * NB_CAT + a.z]; acc[j] = fmaf(s, s, acc[j]); }
            if (a.w == b.w) { const float s = stdv[3 * NB_CAT + a.w]; acc[j] = fmaf(s, s, acc[j]); }
        }
    }

    // prologue: stage slice 0 (all threads, direct copy — no persistent regs)
#pragma unroll
    for (int it = 0; it < 8; ++it) sh[tid + it * 1024] = tsm[tid + it * 1024];
    __syncthreads();

#pragma unroll
    for (int s = 0; s < NSLICE; ++s) {
        if (tid < NLDS_THR) {
            // LDS gathers for slice s = (col s>>1, half s&1)
            const int c = s >> 1;
#pragma unroll
            for (int j = 0; j < 4; ++j) {
                const int xi = comp4(xv[j], c);
                const int yi = comp4(yv[j], c);
                acc[j] = dot8_f16(sh[xi], sh[yi], acc[j]);
            }
        } else {
            // TCP chunk: 96 pairs of this block's tail region, R4 geometry
            const int tt = tid - NLDS_THR;   // 0..191
            const int gi = tt >> 3;          // group 0..23
            const int q  = tt & 7;
            const int c  = q >> 1;
            const int hs = q & 1;
            const int rb = c * NB_CAT;
#pragma unroll
            for (int it = 0; it < 2; ++it) {
                const int S  = base + LDS_PPB + s * TCP_PPP + it * 48;
                const int pA = S + gi;
                const int pB = S + 24 + gi;
                const int xiA = x[pA * 4 + c], yiA = y[pA * 4 + c];
                const int xiB = x[pB * 4 + c], yiB = y[pB * 4 + c];
                const uint4 aA = trm[(size_t)(rb + xiA) * 2 + hs];
                const uint4 bA = trm[(size_t)(rb + yiA) * 2 + hs];
                const uint4 aB = trm[(size_t)(rb + xiB) * 2 + hs];
                const uint4 bB = trm[(size_t)(rb + yiB) * 2 + hs];
                float vA = dot8_f16(aA, bA, 0.f);
                float vB = dot8_f16(aB, bB, 0.f);
                if (hs == 0 && xiA == yiA) { const float sd = stdv[rb + xiA]; vA = fmaf(sd, sd, vA); }
                if (hs == 0 && xiB == yiB) { const float sd = stdv[rb + xiB]; vB = fmaf(sd, sd, vB); }
                vA = groupsum8(vA);
                vB = groupsum8(vB);
                if (q < 2) {
                    const int   p = (q == 0) ? pA : pB;
                    const float v = (q == 0) ? vA : vB;
                    out[p] = v;
                }
            }
        }
        __syncthreads();
        if (s < NSLICE - 1) {
            const uint4* src = tsm + (size_t)(s + 1) * SLICE_ROWS;
#pragma unroll
            for (int it = 0; it < 8; ++it) sh[tid + it * 1024] = src[tid + it * 1024];
            __syncthreads();
        }
    }

    if (tid < NLDS_THR) {
#pragma unroll
        for (int k = 0; k < 4; ++k) out[base + tid + k * NLDS_THR] = acc[k];
    }
}

// ---------- fallback (fp32 direct gather, R3 structure) if ws too small ----------
__global__ __launch_bounds__(256) void fallback_kernel(
    const int* __restrict__ x, const int* __restrict__ y,
    const float4* __restrict__ cf, const float* __restrict__ stdv,
    float* __restrict__ out)
{
    const int tid = threadIdx.x;
    const int q = tid & 15, gi = tid >> 4, c = q >> 2, s = q & 3;
    const int p0 = blockIdx.x * 32 + gi, p1 = p0 + 16;
    const int rb = c * NB_CAT;
    const int xi0 = x[p0*4+c], yi0 = y[p0*4+c], xi1 = x[p1*4+c], yi1 = y[p1*4+c];
    const float4 a0 = cf[(size_t)(rb+xi0)*4 + s], b0 = cf[(size_t)(rb+yi0)*4 + s];
    const float4 a1 = cf[(size_t)(rb+xi1)*4 + s], b1 = cf[(size_t)(rb+yi1)*4 + s];
    float v0 = a0.x*b0.x; v0 = fmaf(a0.y,b0.y,v0); v0 = fmaf(a0.z,b0.z,v0); v0 = fmaf(a0.w,b0.w,v0);
    float v1 = a1.x*b1.x; v1 = fmaf(a1.y,b1.y,v1); v1 = fmaf(a1.z,b1.z,v1); v1 = fmaf(a1.w,b1.w,v1);
    if (s == 0 && xi0 == yi0) { float sd = stdv[rb+xi0]; v0 = fmaf(sd,sd,v0); }
    if (s == 0 && xi1 == yi1) { float sd = stdv[rb+xi1]; v1 = fmaf(sd,sd,v1); }
    int t;
    t = __builtin_amdgcn_update_dpp(0, __float_as_int(v0), 0xB1, 0xF, 0xF, true); v0 += __int_as_float(t);
    t = __builtin_amdgcn_update_dpp(0, __float_as_int(v0), 0x4E, 0xF, 0xF, true); v0 += __int_as_float(t);
    t = __builtin_amdgcn_update_dpp(0, __float_as_int(v0), 0x141,0xF, 0xF, true); v0 += __int_as_float(t);
    t = __builtin_amdgcn_update_dpp(0, __float_as_int(v0), 0x128,0xF, 0xF, true); v0 += __int_as_float(t);
    t = __builtin_amdgcn_update_dpp(0, __float_as_int(v1), 0xB1, 0xF, 0xF, true); v1 += __int_as_float(t);
    t = __builtin_amdgcn_update_dpp(0, __float_as_int(v1), 0x4E, 0xF, 0xF, true); v1 += __int_as_float(t);
    t = __builtin_amdgcn_update_dpp(0, __float_as_int(v1), 0x141,0xF, 0xF, true); v1 += __int_as_float(t);
    t = __builtin_amdgcn_update_dpp(0, __float_as_int(v1), 0x128,0xF, 0xF, true); v1 += __int_as_float(t);
    if (q == 0) { out[p0] = v0; out[p1] = v1; }
}

extern "C" void kernel_launch(void* const* d_in, const int* in_sizes, int n_in,
                              void* d_out, int out_size, void* d_ws, size_t ws_size,
                              hipStream_t stream) {
    const int*   x    = (const int*)d_in[0];
    const int*   y    = (const int*)d_in[1];
    const float* cf   = (const float*)d_in[2];
    const float* stdv = (const float*)d_in[3];
    float*       out  = (float*)d_out;

    if (ws_size < WS_NEED) {
        fallback_kernel<<<N_PAIRS / 32, 256, 0, stream>>>(
            x, y, (const float4*)cf, stdv, out);
        return;
    }

    (void)hipFuncSetAttribute(
        reinterpret_cast<const void*>(&IndexKernel_32238024524411_kernel),
        hipFuncAttributeMaxDynamicSharedMemorySize, LDS_BYTES);

    uint4* tsm = (uint4*)d_ws;
    uint4* trm = (uint4*)((char*)d_ws + TBL_SM_BYTES);

    pack_f16_kernel<<<NSLICE * NB_CAT / 256, 256, 0, stream>>>(
        (const float4*)cf, tsm, trm);

    IndexKernel_32238024524411_kernel<<<N_PAIRS / 4096, 1024, LDS_BYTES, stream>>>(
        (const int4*)x, (const int4*)y, x, y, tsm, trm, stdv, out);
}

// Round 12
// 94.122 us; speedup vs baseline: 1.6417x; 1.0819x over previous
//
#include <hip/hip_runtime.h>

#define NB_CAT  8192
#define RANK    16
#define N_COLS  4
#define N_PAIRS 1048576

#define NSLICE      8                          // (col, rank-half), b128 rows
#define SLICE_ROWS  NB_CAT
#define SLICE_BYTES (SLICE_ROWS * 16)          // 128 KB
#define TBL_BYTES   ((size_t)NSLICE * SLICE_BYTES)   // 1 MB
#define LDS_BYTES   SLICE_BYTES                // single 128 KB buffer
#define PART_BYTES  ((size_t)N_PAIRS * 4)      // 4 MB per partial
#define WS_NEED     (TBL_BYTES + 2 * PART_BYTES)     // 9 MB

typedef _Float16 half2_t __attribute__((ext_vector_type(2)));

#if defined(__has_builtin)
#if __has_builtin(__builtin_amdgcn_fdot2)
#define HAVE_FDOT2 1
#endif
#endif

__device__ __forceinline__ float dot8_f16(uint4 A, uint4 B, float acc) {
#ifdef HAVE_FDOT2
    acc = __builtin_amdgcn_fdot2(__builtin_bit_cast(half2_t, A.x), __builtin_bit_cast(half2_t, B.x), acc, false);
    acc = __builtin_amdgcn_fdot2(__builtin_bit_cast(half2_t, A.y), __builtin_bit_cast(half2_t, B.y), acc, false);
    acc = __builtin_amdgcn_fdot2(__builtin_bit_cast(half2_t, A.z), __builtin_bit_cast(half2_t, B.z), acc, false);
    acc = __builtin_amdgcn_fdot2(__builtin_bit_cast(half2_t, A.w), __builtin_bit_cast(half2_t, B.w), acc, false);
#else
    half2_t ax = __builtin_bit_cast(half2_t, A.x), bx = __builtin_bit_cast(half2_t, B.x);
    half2_t ay = __builtin_bit_cast(half2_t, A.y), by = __builtin_bit_cast(half2_t, B.y);
    half2_t az = __builtin_bit_cast(half2_t, A.z), bz = __builtin_bit_cast(half2_t, B.z);
    half2_t aw = __builtin_bit_cast(half2_t, A.w), bw = __builtin_bit_cast(half2_t, B.w);
    acc = fmaf((float)ax[0], (float)bx[0], acc); acc = fmaf((float)ax[1], (float)bx[1], acc);
    acc = fmaf((float)ay[0], (float)by[0], acc); acc = fmaf((float)ay[1], (float)by[1], acc);
    acc = fmaf((float)az[0], (float)bz[0], acc); acc = fmaf((float)az[1], (float)bz[1], acc);
    acc = fmaf((float)aw[0], (float)bw[0], acc); acc = fmaf((float)aw[1], (float)bw[1], acc);
#endif
    return acc;
}

// ---------- prep: fp32 cf -> fp16 table, layout [slice=(c,h)][cat] row = 16 B ----------
__global__ __launch_bounds__(256) void pack_f16_kernel(
    const float4* __restrict__ src, uint4* __restrict__ dst)
{
    const int g = blockIdx.x * 256 + threadIdx.x;   // slice*8192 + cat, 65536
    const int s = g >> 13;
    const int k = g & (NB_CAT - 1);
    const int c = s >> 1, h = s & 1;

    const float4 f0 = src[(c * NB_CAT + k) * 4 + h * 2];
    const float4 f1 = src[(c * NB_CAT + k) * 4 + h * 2 + 1];

    half2_t p0 = {(_Float16)f0.x, (_Float16)f0.y};
    half2_t p1 = {(_Float16)f0.z, (_Float16)f0.w};
    half2_t p2 = {(_Float16)f1.x, (_Float16)f1.y};
    half2_t p3 = {(_Float16)f1.z, (_Float16)f1.w};

    uint4 u;
    u.x = __builtin_bit_cast(unsigned int, p0);
    u.y = __builtin_bit_cast(unsigned int, p1);
    u.z = __builtin_bit_cast(unsigned int, p2);
    u.w = __builtin_bit_cast(unsigned int, p3);
    dst[g] = u;
}

// ---------- main: 2-col split + b128 rows + 4 phases + named-reg prefetch ----------
// 256 blocks (2 col-groups x 128 chunks) x 1024 threads, 128 KB dyn LDS.
// Group g: cols {2g,2g+1} = slices [4g,4g+4), 8192 pairs/block (8/thread).
// Phase s (cl=s>>1,h=s&1): prefetch slice s+1 into 8 NAMED uint4 regs (stays
// in flight across raw lgkm-only barriers), compute (2 ds_read_b128 + 4 fdot2
// per pair), barrier, ds_write prefetched slice, barrier.
__global__ __launch_bounds__(1024, 1) void IndexKernel_32238024524411_kernel(
    const int2*  __restrict__ x2,    // (N_PAIRS,2) int2; elem 2p+g = cols {2g,2g+1}
    const int2*  __restrict__ y2,
    const uint4* __restrict__ tbl,   // fp16 slice-major table in ws
    const float* __restrict__ stdv,  // (N_COLS, NB_CAT) fp32
    float*       __restrict__ part)  // (2, N_PAIRS) partials in ws
{
    extern __shared__ uint4 sh[];    // 8192 rows = 128 KB

    const int tid   = threadIdx.x;
    const int g     = blockIdx.x >> 7;     // col-group 0/1
    const int chunk = blockIdx.x & 127;
    const int base  = chunk * 8192 + tid;  // pairs: base + j*1024

    const uint4* gtbl = tbl + (size_t)(g * 4) * SLICE_ROWS;

    int2 xi[8], yi[8];
#pragma unroll
    for (int j = 0; j < 8; ++j) {
        const size_t p = (size_t)(base + j * 1024);
        xi[j] = x2[p * 2 + g];
        yi[j] = y2[p * 2 + g];
    }

    float acc[8] = {0.f, 0.f, 0.f, 0.f, 0.f, 0.f, 0.f, 0.f};

    // diagonal std^2 pre-pass for this group's two columns
    const float* sd0 = stdv + (size_t)(2 * g) * NB_CAT;
    const float* sd1 = stdv + (size_t)(2 * g + 1) * NB_CAT;
#pragma unroll
    for (int j = 0; j < 8; ++j) {
        if (xi[j].x == yi[j].x) { const float s = sd0[xi[j].x]; acc[j] = fmaf(s, s, acc[j]); }
        if (xi[j].y == yi[j].y) { const float s = sd1[xi[j].y]; acc[j] = fmaf(s, s, acc[j]); }
    }

    // stage slice 0 directly (compiler temps only)
#pragma unroll
    for (int it = 0; it < 8; ++it) sh[tid + it * 1024] = gtbl[tid + it * 1024];
    asm volatile("s_waitcnt lgkmcnt(0)" ::: "memory");
    __builtin_amdgcn_s_barrier();
    asm volatile("" ::: "memory");

    // named prefetch registers — no array, guaranteed SROA (R10 lesson)
    uint4 t0, t1, t2, t3, t4, t5, t6, t7;

#define PHASE(S)                                                               \
    {                                                                          \
        constexpr int s  = (S);                                                \
        constexpr int cl = s >> 1;   /* local col 0/1 */                       \
        if (s < 3) {                                                           \
            const uint4* nsrc = gtbl + (size_t)(s + 1) * SLICE_ROWS;           \
            t0 = nsrc[tid];             t1 = nsrc[tid + 1024];                 \
            t2 = nsrc[tid + 2 * 1024];  t3 = nsrc[tid + 3 * 1024];             \
            t4 = nsrc[tid + 4 * 1024];  t5 = nsrc[tid + 5 * 1024];             \
            t6 = nsrc[tid + 6 * 1024];  t7 = nsrc[tid + 7 * 1024];             \
        }                                                                      \
        asm volatile("" ::: "memory");                                         \
        _Pragma("unroll")                                                      \
        for (int j = 0; j < 8; ++j) {                                          \
            const int a = cl ? xi[j].y : xi[j].x;                              \
            const int b = cl ? yi[j].y : yi[j].x;                              \
            acc[j] = dot8_f16(sh[a], sh[b], acc[j]);                           \
        }                                                                      \
        if (s < 3) {                                                           \
            asm volatile("s_waitcnt lgkmcnt(0)" ::: "memory");                 \
            __builtin_amdgcn_s_barrier();                                      \
            asm volatile("" ::: "memory");                                     \
            sh[tid]            = t0;  sh[tid + 1024]     = t1;                 \
            sh[tid + 2 * 1024] = t2;  sh[tid + 3 * 1024] = t3;                 \
            sh[tid + 4 * 1024] = t4;  sh[tid + 5 * 1024] = t5;                 \
            sh[tid + 6 * 1024] = t6;  sh[tid + 7 * 1024] = t7;                 \
            asm volatile("s_waitcnt lgkmcnt(0)" ::: "memory");                 \
            __builtin_amdgcn_s_barrier();                                      \
            asm volatile("" ::: "memory");                                     \
        }                                                                      \
    }

    PHASE(0) PHASE(1) PHASE(2) PHASE(3)
#undef PHASE

    float* my = part + (size_t)g * N_PAIRS;
#pragma unroll
    for (int j = 0; j < 8; ++j) {
        my[base + j * 1024] = acc[j];
    }
}

// ---------- reduce: out = part0 + part1 ----------
__global__ __launch_bounds__(256) void reduce_kernel(
    const float4* __restrict__ p0, const float4* __restrict__ p1,
    float4* __restrict__ out)
{
    const int i = blockIdx.x * 256 + threadIdx.x;
    const float4 a = p0[i];
    const float4 b = p1[i];
    out[i] = float4{a.x + b.x, a.y + b.y, a.z + b.z, a.w + b.w};
}

// ---------- fallback (fp32 direct gather, R3 structure) if ws too small ----------
__global__ __launch_bounds__(256) void fallback_kernel(
    const int* __restrict__ x, const int* __restrict__ y,
    const float4* __restrict__ cf, const float* __restrict__ stdv,
    float* __restrict__ out)
{
    const int tid = threadIdx.x;
    const int q = tid & 15, gi = tid >> 4, c = q >> 2, s = q & 3;
    const int p0 = blockIdx.x * 32 + gi, p1 = p0 + 16;
    const int rb = c * NB_CAT;
    const int xi0 = x[p0*4+c], yi0 = y[p0*4+c], xi1 = x[p1*4+c], yi1 = y[p1*4+c];
    const float4 a0 = cf[(size_t)(rb+xi0)*4 + s], b0 = cf[(size_t)(rb+yi0)*4 + s];
    const float4 a1 = cf[(size_t)(rb+xi1)*4 + s], b1 = cf[(size_t)(rb+yi1)*4 + s];
    float v0 = a0.x*b0.x; v0 = fmaf(a0.y,b0.y,v0); v0 = fmaf(a0.z,b0.z,v0); v0 = fmaf(a0.w,b0.w,v0);
    float v1 = a1.x*b1.x; v1 = fmaf(a1.y,b1.y,v1); v1 = fmaf(a1.z,b1.z,v1); v1 = fmaf(a1.w,b1.w,v1);
    if (s == 0 && xi0 == yi0) { float sd = stdv[rb+xi0]; v0 = fmaf(sd,sd,v0); }
    if (s == 0 && xi1 == yi1) { float sd = stdv[rb+xi1]; v1 = fmaf(sd,sd,v1); }
    int t;
    t = __builtin_amdgcn_update_dpp(0, __float_as_int(v0), 0xB1, 0xF, 0xF, true); v0 += __int_as_float(t);
    t = __builtin_amdgcn_update_dpp(0, __float_as_int(v0), 0x4E, 0xF, 0xF, true); v0 += __int_as_float(t);
    t = __builtin_amdgcn_update_dpp(0, __float_as_int(v0), 0x141,0xF, 0xF, true); v0 += __int_as_float(t);
    t = __builtin_amdgcn_update_dpp(0, __float_as_int(v0), 0x128,0xF, 0xF, true); v0 += __int_as_float(t);
    t = __builtin_amdgcn_update_dpp(0, __float_as_int(v1), 0xB1, 0xF, 0xF, true); v1 += __int_as_float(t);
    t = __builtin_amdgcn_update_dpp(0, __float_as_int(v1), 0x4E, 0xF, 0xF, true); v1 += __int_as_float(t);
    t = __builtin_amdgcn_update_dpp(0, __float_as_int(v1), 0x141,0xF, 0xF, true); v1 += __int_as_float(t);
    t = __builtin_amdgcn_update_dpp(0, __float_as_int(v1), 0x128,0xF, 0xF, true); v1 += __int_as_float(t);
    if (q == 0) { out[p0] = v0; out[p1] = v1; }
}

extern "C" void kernel_launch(void* const* d_in, const int* in_sizes, int n_in,
                              void* d_out, int out_size, void* d_ws, size_t ws_size,
                              hipStream_t stream) {
    const int*   x    = (const int*)d_in[0];
    const int*   y    = (const int*)d_in[1];
    const float* cf   = (const float*)d_in[2];
    const float* stdv = (const float*)d_in[3];
    float*       out  = (float*)d_out;

    if (ws_size < WS_NEED) {
        fallback_kernel<<<N_PAIRS / 32, 256, 0, stream>>>(
            x, y, (const float4*)cf, stdv, out);
        return;
    }

    (void)hipFuncSetAttribute(
        reinterpret_cast<const void*>(&IndexKernel_32238024524411_kernel),
        hipFuncAttributeMaxDynamicSharedMemorySize, LDS_BYTES);

    uint4* tbl  = (uint4*)d_ws;
    float* part = (float*)((char*)d_ws + TBL_BYTES);   // (2, N_PAIRS)

    pack_f16_kernel<<<NSLICE * NB_CAT / 256, 256, 0, stream>>>(
        (const float4*)cf, tbl);

    IndexKernel_32238024524411_kernel<<<256, 1024, LDS_BYTES, stream>>>(
        (const int2*)x, (const int2*)y, tbl, stdv, part);

    reduce_kernel<<<N_PAIRS / 4 / 256, 256, 0, stream>>>(
        (const float4*)part, (const float4*)(part + N_PAIRS), (float4*)out);
}